// Round 9
// baseline (49779.568 us; speedup 1.0000x reference)
//
#include <hip/hip_runtime.h>

#define DI __device__ __forceinline__

typedef __bf16  bf16x8 __attribute__((ext_vector_type(8)));
typedef float   f32x4  __attribute__((ext_vector_type(4)));
typedef unsigned short u16;
typedef unsigned int   u32;
typedef unsigned long long u64;

DI u16 f2bf(float f){ u32 u=__float_as_uint(f); u32 r=0x7fffu+((u>>16)&1u); return (u16)((u+r)>>16); }
DI float bf2f(u16 h){ return __uint_as_float(((u32)h)<<16); }

union U16x8 { u16 u[8]; uint4 v; };
union ABu   { uint4 u; bf16x8 b; };

#define MFMA(a,b,c) __builtin_amdgcn_mfma_f32_16x16x32_bf16((a),(b),(c),0,0,0)
#define SCHED0() __builtin_amdgcn_sched_barrier(0)
#define SBAR()   __builtin_amdgcn_s_barrier()

// h-state 8B load: device-coherent (L3 coherence point), r4-proven model
DI void aload8(uint2& d, const void* p){
  asm volatile("global_load_dwordx2 %0, %1, off sc0 sc1" : "=&v"(d) : "v"(p) : "memory");
}
// static weights: plain cached 16B load -> registers (XCD-L2-resident)
DI void wload(uint4& d, const void* p){
  asm volatile("global_load_dwordx4 %0, %1, off" : "=&v"(d) : "v"(p) : "memory");
}
// coherent 8B store (u64 input constraint is valid)
DI void st8c(void* p, u64 v){
  asm volatile("global_store_dwordx2 %0, %1, off sc0 sc1" :: "v"(p), "v"(v) : "memory");
}
template<int N> DI void vw(){ asm volatile("s_waitcnt vmcnt(%0)" :: "n"(N) : "memory"); }
DI void lgkm0(){ asm volatile("s_waitcnt lgkmcnt(0)" ::: "memory"); }
DI void spinw(u32* f, u32 tgt){
  while (__hip_atomic_load(f, __ATOMIC_RELAXED, __HIP_MEMORY_SCOPE_AGENT) < tgt)
    __builtin_amdgcn_s_sleep(8);
}

// ---- problem constants
#define Tn 512
#define Bn 2048
#define Hn 512

// ---- workspace layout (bytes). Hybrid W: per (jg,k32) 4 planes [r|z|nh|nl]
#define OFF_WH0   0ull
#define OFF_WI1   2097152ull
#define OFF_WH1   4194304ull
#define OFF_WI0   6291456ull
#define OFF_H0HI  6422528ull
#define OFF_H0LO  10616832ull
#define OFF_H1HI  14811136ull
#define OFF_H1LO  19005440ull
#define OFF_FLAGS 23199744ull
// flags: [2][512][64] u32 = 262144 B -> end 23461888

#define PLANE 1048576   // u16 per parity plane (2048x512)
// LDS: A slots 2x4KB [0,8192) | transpose 16KB [8192,24576) | pad to 84KB
#define TROFF 8192

// =====================================================================
// prep_w: fp32 [1536 x 512] -> hybrid frag-linear subtiles.
// block(jg,k32) = 4 planes x 512 u16: 0=r 1=z 2=n-hi 3=n-lo.
// lane t64 = (j&15) + (k>>3)*16, 8 u16 (k&7) each.
// =====================================================================
__global__ __launch_bounds__(256) void prep_w(const float* __restrict__ w0,
                                              const float* __restrict__ w1,
                                              const float* __restrict__ w2,
                                              u16* __restrict__ dst){
  int tid = blockIdx.x*256 + threadIdx.x;        // 393216 total
  int p = tid / 131072, rem = tid % 131072;      // 0=WH0 1=WI1 2=WH1
  int sub = rem >> 6, t64 = rem & 63;
  int plane = sub & 3, k32 = (sub>>2) & 15, jg = sub >> 6;
  int g = (plane < 2) ? plane : 2;
  int jj = t64 & 15, koct = t64 >> 4;
  const float* src = (p==0)?w0:((p==1)?w1:w2);
  const float* sp = src + (size_t)(g*512 + jg*16 + jj)*512 + k32*32 + koct*8;
  U16x8 o;
#pragma unroll
  for (int i=0;i<8;++i){
    float v = sp[i]; u16 h = f2bf(v);
    o.u[i] = (plane==3) ? f2bf(v - bf2f(h)) : h;
  }
  u16* d = dst + (size_t)p*1048576 + ((size_t)((jg*16 + k32)*4 + plane))*512 + (size_t)t64*8;
  *(uint4*)d = o.v;
}

// W_ih0 [1536x16] -> per jg: 4 planes, [v|v] duplicated across k16-halves
__global__ __launch_bounds__(256) void prep_wi0(const float* __restrict__ w,
                                                u16* __restrict__ dst){
  int tid = blockIdx.x*256 + threadIdx.x;        // 8192 total
  if (tid >= 8192) return;
  int jg = tid >> 8, rem = tid & 255;
  int plane = rem >> 6, t64 = rem & 63;
  int jj = t64 & 15, koct = t64 >> 4, col8 = koct & 1;
  int g = (plane < 2) ? plane : 2;
  const float* sp = w + (size_t)(g*512 + jg*16 + jj)*16 + col8*8;
  U16x8 o;
#pragma unroll
  for (int i=0;i<8;++i){
    float v = sp[i]; u16 h = f2bf(v);
    o.u[i] = (plane==3) ? f2bf(v - bf2f(h)) : h;
  }
  u16* d = dst + ((size_t)(jg*4 + plane))*512 + (size_t)t64*8;
  *(uint4*)d = o.v;
}

// zero parity-1 h planes (initial state) + flags
__global__ __launch_bounds__(256) void zero_ws(char* __restrict__ ws){
  int tid = blockIdx.x*256 + threadIdx.x;
  if (tid >= 540672) return;
  uint4 z = {0u,0u,0u,0u};
  size_t o;
  if      (tid < 131072) o = OFF_H0HI + 2097152 + (size_t)tid*16;
  else if (tid < 262144) o = OFF_H0LO + 2097152 + (size_t)(tid-131072)*16;
  else if (tid < 393216) o = OFF_H1HI + 2097152 + (size_t)(tid-262144)*16;
  else if (tid < 524288) o = OFF_H1LO + 2097152 + (size_t)(tid-393216)*16;
  else                   o = OFF_FLAGS + (size_t)(tid-524288)*16;
  *(uint4*)(ws + o) = z;
}

struct PA {
  const u16 *WI0, *WH0, *WI1, *WH1;
  const float *x;
  u16 *H0HI, *H0LO, *H1HI, *H1LO;
  u32 *flags;                       // [2][512][64 mt] publish counts (target 4)
  const float *bi0,*bh0,*bi1,*bh1;
};

// =====================================================================
// One layer-step. Block 512 thr (8 waves), tile 32 rows x 128 hidden cols.
// Wave wv owns jg = jt*8+wv (16 cols) x all 32 rows (2 m-frags).
// W (hybrid, 4 planes) -> REGISTERS via plain loads (XCD-L2-resident).
// A (h hi/lo) -> 8B sc0sc1 per wave -> LDS 2-slot (shared by 8 waves).
// Uniform FIFO 5 VMEM/wave/group [W,W,W,W,A]; depth-3; counted vmcnt.
// acc[m][0]=r(i+h) [1]=z(i+h) [2]=i_n [3]=h_n
// =====================================================================
template<int L>
DI void layer_run(const PA& a, int s, char* smem, int tid, int lane, int wv,
                  int mt, int jt, const float* xs,
                  const u16* AhiI, const u16* AloI,
                  const u16* AhiH, const u16* AloH,
                  u16* OHI, u16* OLO,
                  float SR, float SZ, float BIN, float BHN,
                  f32x4 (&hp)[2],
                  u32* sp1, u32* sp2, u32* pub)
{
  constexpr int NI = (L==0) ? 1 : 16;
  constexpr int NT = (L==0) ? 17 : 32;
  const u16* Wi = (L==0) ? a.WI0 : a.WI1;
  const u16* Wh = (L==0) ? a.WH0 : a.WH1;
  const int jg = jt*8 + wv;
  const int asub = wv >> 1;          // 0..3 = m*2+hl
  const int ahalf = wv & 1;

  f32x4 acc[2][4];
#pragma unroll
  for (int m=0;m<2;++m)
#pragma unroll
    for (int o=0;o<4;++o){ f32x4 z={0.f,0.f,0.f,0.f}; acc[m][o]=z; }

  uint4 wreg[3][4];
  uint2 areg[3];

  auto issueW = [&](int t){
    const u16* wb; int k32 = 0; bool x0 = false;
    if (L==0){ if (t==0){ wb=Wi; x0=true; } else { wb=Wh; k32=t-1; } }
    else { if (t<16){ wb=Wi; k32=t; } else { wb=Wh; k32=t-16; } }
#pragma unroll
    for (int pl=0; pl<4; ++pl){
      size_t off = x0 ? ((size_t)(jg*4 + pl))*512
                      : ((size_t)((jg*16 + k32)*4 + pl))*512;
      wload(wreg[t%3][pl], wb + off + (size_t)lane*8);
    }
  };
  auto issueA = [&](int t){
    const u16* ph; int k32;
    if (L==0){ ph = (asub&1) ? AloH : AhiH; k32 = (t==0) ? 0 : (t-1); }  // t=0 dummy
    else if (t < 16){ ph = (asub&1) ? AloI : AhiI; k32 = t; }
    else { ph = (asub&1) ? AloH : AhiH; k32 = t-16; }
    size_t off = ((size_t)((mt*2 + (asub>>1))*16 + k32))*512 + (size_t)(ahalf*256 + lane*4);
    aload8(areg[t%3], ph + off);
  };
  auto writeA = [&](int t){
    *(uint2*)(smem + (t&1)*4096 + asub*1024 + ahalf*512 + (size_t)lane*8) = areg[t%3];
  };
  auto compute = [&](int t){
    const char* sl = smem + (t&1)*4096;
    ABu cr, cz, cnh, cnl;
    cr.u = wreg[t%3][0]; cz.u = wreg[t%3][1];
    cnh.u = wreg[t%3][2]; cnl.u = wreg[t%3][3];
    const int gn = (t < NI) ? 2 : 3;
#pragma unroll
    for (int m=0;m<2;++m){
      bf16x8 ah = *(const bf16x8*)(sl + (m*2+0)*1024 + (size_t)lane*16);
      bf16x8 al = *(const bf16x8*)(sl + (m*2+1)*1024 + (size_t)lane*16);
      acc[m][0]  = MFMA(ah, cr.b,  acc[m][0]);
      acc[m][0]  = MFMA(al, cr.b,  acc[m][0]);
      acc[m][1]  = MFMA(ah, cz.b,  acc[m][1]);
      acc[m][1]  = MFMA(al, cz.b,  acc[m][1]);
      acc[m][gn] = MFMA(ah, cnh.b, acc[m][gn]);
      acc[m][gn] = MFMA(ah, cnl.b, acc[m][gn]);
      acc[m][gn] = MFMA(al, cnh.b, acc[m][gn]);
    }
  };

  // ---- L0: stage x into A slot 0 ([x_hi k0-15|x_lo k16-31] in "hi" subtiles,
  //      zeros in "lo" subtiles so uniform 3-product MFMA adds 0)
  if (L==0){
    if (tid < 64){
      int row = tid >> 1, half = tid & 1;
      const float* xr = xs + (size_t)(mt*32 + row)*16 + half*8;
      U16x8 H, Lo;
#pragma unroll
      for (int i=0;i<8;++i){ float f = xr[i]; u16 h = f2bf(f); H.u[i]=h; Lo.u[i]=f2bf(f - bf2f(h)); }
      char* b0 = smem + (row>>4)*2048;
      *(uint4*)(b0 + (size_t)((row&15) + half*16)*16)     = H.v;
      *(uint4*)(b0 + (size_t)((row&15) + (2+half)*16)*16) = Lo.v;
    } else if (tid < 192){
      int idx = tid - 64;
      uint4 z = {0u,0u,0u,0u};
      *(uint4*)(smem + (size_t)(1 + 2*(idx>>6))*1024 + (size_t)(idx&63)*16) = z;
    }
  }

  // ---- prologue: W(0..2) (static; hides under spin) -> spin -> barrier -> A(0..2)
  issueW(0); issueW(1); issueW(2);
  if (tid == 0){
    if (sp1) spinw(sp1, 4u);
    if (sp2) spinw(sp2, 4u);
  }
  lgkm0();
  SBAR();
  issueA(0); issueA(1); issueA(2);
  vw<2>(); SCHED0();
  if (L != 0) writeA(0);           // L0: slot0 already holds x

  // ---- main loop: wait -> barrier -> writeA(t+1) -> MFMA(t) -> issue g(t+3)
#pragma unroll
  for (int t=0; t<NT; ++t){
    if (t==0)            { vw<1>(); }
    else if (t+2 <= NT-1){ vw<5>(); }
    else                 { vw<0>(); }
    SCHED0();
    lgkm0();
    SBAR();
    if (t+1 < NT) writeA(t+1);
    compute(t);
    if (t+3 <= NT-1){ issueW(t+3); issueA(t+3); }
  }

  // ---- epilogue: gates -> h -> LDS transpose -> coalesced sc0sc1 stores
  const int col = lane & 15, rg = lane >> 4;
#pragma unroll
  for (int m=0;m<2;++m){
    int chunk = m*4 + (wv>>1);
    char* thi = smem + TROFF + chunk*1024;
    char* tlo = thi + 8192;
#pragma unroll
    for (int r=0;r<4;++r){
      float pr  = acc[m][0][r] + SR;
      float pz  = acc[m][1][r] + SZ;
      float pin = acc[m][2][r] + BIN;
      float phn = acc[m][3][r] + BHN;
      float rgt = 1.f/(1.f + __expf(-pr));
      float zgt = 1.f/(1.f + __expf(-pz));
      float e2  = __expf(2.f*(pin + rgt*phn));
      float nn  = 1.f - 2.f/(e2 + 1.f);           // tanh, overflow-safe
      float hv  = hp[m][r];
      float hnv = (1.f - zgt)*nn + zgt*hv;
      hp[m][r] = hnv;
      u16 hi = f2bf(hnv), lo = f2bf(hnv - bf2f(hi));
      int idx = ((rg*4 + r) + ((wv*2 + (col>>3))&3)*16)*8 + (col&7);
      *(u16*)(thi + idx*2) = hi;
      *(u16*)(tlo + idx*2) = lo;
    }
  }
  lgkm0();
  SBAR();
  {
    int region = tid >> 8, tt = tid & 255;
    int chunk = tt >> 5;
    const char* src = smem + TROFF + region*8192 + (size_t)tt*32;
    u16* base = (region ? OLO : OHI)
              + (size_t)(mt*2 + (chunk>>2))*8192 + (size_t)(jt*4 + (chunk&3))*512
              + (size_t)(tt&31)*16;
    st8c(base,      *(const u64*)(src));
    st8c(base + 4,  *(const u64*)(src + 8));
    st8c(base + 8,  *(const u64*)(src + 16));
    st8c(base + 12, *(const u64*)(src + 24));
  }
  vw<0>(); SCHED0();
  SBAR();
  if (tid == 0)
    __hip_atomic_fetch_add(pub, 1u, __ATOMIC_RELAXED, __HIP_MEMORY_SCOPE_AGENT);
}

// =====================================================================
// Persistent kernel: 256 blocks x 512 thr (1/CU via 84KB LDS -> 2 waves/SIMD).
// jt = bid&3 (XCD-pinned 1.5MB W slice, L2-resident), mt = bid>>2 (32 rows).
// 64 independent mt-chains; sync = monotone flags (target 4 jt-publishers).
// =====================================================================
__global__ __launch_bounds__(512, 1) void gru_persist(PA a){
  __shared__ __align__(16) char smem[86016];
  const int tid = threadIdx.x, lane = tid & 63, wv = tid >> 6;
  const int bid = blockIdx.x;
  const int jt = bid & 3, mt = bid >> 2;

  const int j = jt*128 + wv*16 + (lane & 15);
  const float SR0 = a.bi0[j] + a.bh0[j];
  const float SZ0 = a.bi0[Hn+j] + a.bh0[Hn+j];
  const float BIN0 = a.bi0[2*Hn+j], BHN0 = a.bh0[2*Hn+j];
  const float SR1 = a.bi1[j] + a.bh1[j];
  const float SZ1 = a.bi1[Hn+j] + a.bh1[Hn+j];
  const float BIN1 = a.bi1[2*Hn+j], BHN1 = a.bh1[2*Hn+j];

  f32x4 hp0[2], hp1[2];
#pragma unroll
  for (int m=0;m<2;++m){ f32x4 z={0.f,0.f,0.f,0.f}; hp0[m]=z; hp1[m]=z; }

  u32* f0 = a.flags;
  u32* f1 = a.flags + 32768;

#pragma unroll 1
  for (int s=0; s<Tn; ++s){
    const size_t P0 = (size_t)(s&1)*PLANE, P1 = (size_t)((s&1)^1)*PLANE;
    layer_run<0>(a, s, smem, tid, lane, wv, mt, jt,
                 a.x + (size_t)s*Bn*16,
                 nullptr, nullptr,
                 a.H0HI + P1, a.H0LO + P1,
                 a.H0HI + P0, a.H0LO + P0,
                 SR0, SZ0, BIN0, BHN0, hp0,
                 (s>0) ? &f0[(size_t)(s-1)*64 + mt] : nullptr, nullptr,
                 &f0[(size_t)s*64 + mt]);
    layer_run<1>(a, s, smem, tid, lane, wv, mt, jt, nullptr,
                 a.H0HI + P0, a.H0LO + P0,
                 a.H1HI + P1, a.H1LO + P1,
                 a.H1HI + P0, a.H1LO + P0,
                 SR1, SZ1, BIN1, BHN1, hp1,
                 &f0[(size_t)s*64 + mt],
                 (s>0) ? &f1[(size_t)(s-1)*64 + mt] : nullptr,
                 &f1[(size_t)s*64 + mt]);
  }
}

// final projection: out[b][o] = h1[b,:] . Wout[o,:] + bout[o]
__global__ __launch_bounds__(64) void outproj(const u16* __restrict__ h1hi,
                                              const u16* __restrict__ h1lo,
                                              const float* __restrict__ Wout,
                                              const float* __restrict__ bout,
                                              float* __restrict__ out){
  int b = blockIdx.x, l = threadIdx.x;
  float acc[8] = {0.f,0.f,0.f,0.f,0.f,0.f,0.f,0.f};
  for (int jj = l; jj < Hn; jj += 64){
    size_t fo = ((size_t)(b>>4)*16 + (jj>>5))*512 + (size_t)((b&15) + ((jj>>3)&3)*16)*8 + (jj&7);
    float hv = bf2f(h1hi[fo]) + bf2f(h1lo[fo]);
#pragma unroll
    for (int o=0;o<8;++o) acc[o] += hv * Wout[o*Hn + jj];
  }
#pragma unroll
  for (int o=0;o<8;++o){
#pragma unroll
    for (int off=32; off; off>>=1) acc[o] += __shfl_xor(acc[o], off);
  }
  if (l == 0){
#pragma unroll
    for (int o=0;o<8;++o) out[b*8+o] = acc[o] + bout[o];
  }
}

extern "C" void kernel_launch(void* const* d_in, const int* in_sizes, int n_in,
                              void* d_out, int out_size, void* d_ws, size_t ws_size,
                              hipStream_t stream){
  (void)in_sizes; (void)n_in; (void)out_size; (void)ws_size;
  const float* x    = (const float*)d_in[0];
  const float* Wih0 = (const float*)d_in[1];
  const float* Whh0 = (const float*)d_in[2];
  const float* bih0 = (const float*)d_in[3];
  const float* bhh0 = (const float*)d_in[4];
  const float* Wih1 = (const float*)d_in[5];
  const float* Whh1 = (const float*)d_in[6];
  const float* bih1 = (const float*)d_in[7];
  const float* bhh1 = (const float*)d_in[8];
  const float* Wout = (const float*)d_in[9];
  const float* bout = (const float*)d_in[10];
  char* ws = (char*)d_ws;

  prep_w  <<<1536, 256, 0, stream>>>(Whh0, Wih1, Whh1, (u16*)(ws + OFF_WH0));
  prep_wi0<<<  32, 256, 0, stream>>>(Wih0, (u16*)(ws + OFF_WI0));
  zero_ws <<<2112, 256, 0, stream>>>(ws);

  PA pa;
  pa.WI0 = (const u16*)(ws + OFF_WI0);
  pa.WH0 = (const u16*)(ws + OFF_WH0);
  pa.WI1 = (const u16*)(ws + OFF_WI1);
  pa.WH1 = (const u16*)(ws + OFF_WH1);
  pa.x = x;
  pa.H0HI = (u16*)(ws + OFF_H0HI); pa.H0LO = (u16*)(ws + OFF_H0LO);
  pa.H1HI = (u16*)(ws + OFF_H1HI); pa.H1LO = (u16*)(ws + OFF_H1LO);
  pa.flags = (u32*)(ws + OFF_FLAGS);
  pa.bi0 = bih0; pa.bh0 = bhh0; pa.bi1 = bih1; pa.bh1 = bhh1;

  gru_persist<<<256, 512, 0, stream>>>(pa);

  outproj<<<2048, 64, 0, stream>>>(
      (const u16*)(ws + OFF_H1HI) + PLANE,
      (const u16*)(ws + OFF_H1LO) + PLANE,
      Wout, bout, (float*)d_out);
}